// Round 4
// baseline (405.544 us; speedup 1.0000x reference)
//
#include <hip/hip_runtime.h>

typedef __bf16 bf16;
typedef __bf16 v8bf __attribute__((ext_vector_type(8)));
typedef __bf16 v4bf __attribute__((ext_vector_type(4)));
typedef float  v4f  __attribute__((ext_vector_type(4)));

#define MFMA16(a,b,c) __builtin_amdgcn_mfma_f32_16x16x32_bf16((a),(b),(c),0,0,0)

// B=2, S=2048, D=1024, H=16, DK=64
static constexpr int Sq = 2048;
static constexpr size_t NI = 4194304;  // B*S*D
static constexpr size_t NW = 1048576;  // D*D

__device__ __forceinline__ void gld_lds16(const void* g, void* l) {
  __builtin_amdgcn_global_load_lds(
      (__attribute__((address_space(1))) unsigned int*)g,
      (__attribute__((address_space(3))) unsigned int*)l,
      16, 0, 0);
}

// ---------------- convert fp32 -> bf16 (q,k,v,wq,wk,wv,wo) ----------------
__global__ __launch_bounds__(256) void convert_kernel(
    const float* __restrict__ q, const float* __restrict__ k, const float* __restrict__ v,
    const float* __restrict__ wq, const float* __restrict__ wk,
    const float* __restrict__ wv, const float* __restrict__ wo,
    bf16* __restrict__ dst)
{
  const int NI4 = 1048576;  // NI/4 = 2^20
  const int NW4 = 262144;   // NW/4 = 2^18
  int idx = blockIdx.x * 256 + threadIdx.x;   // total 4194304
  const float* src; size_t dstoff; int local;
  if (idx < 3 * NI4) {
    int a = idx >> 20; local = idx & (NI4 - 1);
    src = (a == 0) ? q : ((a == 1) ? k : v);
    dstoff = (size_t)a * NI;
  } else {
    int t = idx - 3 * NI4;
    int a = t >> 18; local = t & (NW4 - 1);
    src = (a == 0) ? wq : ((a == 1) ? wk : ((a == 2) ? wv : wo));
    dstoff = 3 * NI + (size_t)a * NW;
  }
  float4 f = ((const float4*)src)[local];
  v4bf hv = { (bf16)f.x, (bf16)f.y, (bf16)f.z, (bf16)f.w };
  *(v4bf*)(dst + dstoff + (size_t)local * 4) = hv;
}

// ---------------- m97-style GEMM: C = A(MxK) * Bw(NxK)^T + bias ----------------
// mode 0: bf16 headsplit [B,H,S,DK]; mode 3: same with *0.125 (Q pre-scale);
// mode 2: bf16 VhT [B,H,DK,S] (8B stores); mode 1: f32 row-major.
__device__ __forceinline__ void gemm_bt_body(
    const bf16* __restrict__ A, const bf16* __restrict__ Bw,
    const float* __restrict__ bias, bf16* __restrict__ outh,
    float* __restrict__ outf, int bm, int bn, int mode)
{
  __shared__ alignas(16) bf16 As[128 * 32];
  __shared__ alignas(16) bf16 Bs[128 * 32];
  const int tid = threadIdx.x;
  const int wave = tid >> 6, lane = tid & 63;
  const int quad = lane >> 4, l15 = lane & 15;
  const int wm = (wave >> 1) * 64, wn = (wave & 1) * 64;
  const int lrow = lane >> 2, lcol = (lane & 3) * 8;

  v4f acc[4][4];
#pragma unroll
  for (int i = 0; i < 4; i++)
#pragma unroll
    for (int j = 0; j < 4; j++) { v4f z = {0.f, 0.f, 0.f, 0.f}; acc[i][j] = z; }

  const bf16* gA = A  + (size_t)(bm + wave * 32 + lrow) * 1024 + lcol;
  const bf16* gB = Bw + (size_t)(bn + wave * 32 + lrow) * 1024 + lcol;
  bf16* lA0 = &As[(wave * 32) * 32];
  bf16* lA1 = &As[(wave * 32 + 16) * 32];
  bf16* lB0 = &Bs[(wave * 32) * 32];
  bf16* lB1 = &Bs[(wave * 32 + 16) * 32];

  for (int k0 = 0; k0 < 1024; k0 += 32) {
    gld_lds16(gA + k0, lA0);
    gld_lds16(gA + 16 * 1024 + k0, lA1);
    gld_lds16(gB + k0, lB0);
    gld_lds16(gB + 16 * 1024 + k0, lB1);
    __syncthreads();
    v8bf af[4], bfr[4];
#pragma unroll
    for (int i = 0; i < 4; i++)
      af[i] = *(const v8bf*)&As[(wm + i * 16 + l15) * 32 + quad * 8];
#pragma unroll
    for (int j = 0; j < 4; j++)
      bfr[j] = *(const v8bf*)&Bs[(wn + j * 16 + l15) * 32 + quad * 8];
#pragma unroll
    for (int i = 0; i < 4; i++)
#pragma unroll
      for (int j = 0; j < 4; j++)
        acc[i][j] = MFMA16(af[i], bfr[j], acc[i][j]);
    __syncthreads();
  }

#pragma unroll
  for (int i = 0; i < 4; i++) {
    const int m0 = bm + wm + i * 16 + quad * 4;
#pragma unroll
    for (int j = 0; j < 4; j++) {
      const int n = bn + wn + j * 16 + l15;
      const float bv = bias[n];
      if (mode == 1) {
#pragma unroll
        for (int r = 0; r < 4; r++)
          outf[(size_t)(m0 + r) * 1024 + n] = acc[i][j][r] + bv;
      } else if (mode == 2) {
        // VhT[bh][dk][s]: consecutive r -> consecutive s -> 8B vector store
        int b_ = m0 >> 11, s_ = m0 & 2047;
        int h_ = n >> 6,  dk = n & 63;
        v4bf pk;
#pragma unroll
        for (int r = 0; r < 4; r++) pk[r] = (bf16)(acc[i][j][r] + bv);
        *(v4bf*)&outh[((size_t)((b_ * 16 + h_) * 64 + dk)) * 2048 + s_] = pk;
      } else {
        const float sc = (mode == 3) ? 0.125f : 1.0f;
        int h_ = n >> 6,  dk = n & 63;
#pragma unroll
        for (int r = 0; r < 4; r++) {
          int m = m0 + r;
          int b_ = m >> 11, s_ = m & 2047;
          outh[(((size_t)(b_ * 16 + h_) * 2048 + s_) << 6) + dk] =
              (bf16)((acc[i][j][r] + bv) * sc);
        }
      }
    }
  }
}

__global__ __launch_bounds__(256, 2) void gemm_proj_kernel(
    const bf16* qb, const bf16* kb, const bf16* vb,
    const bf16* wqb, const bf16* wkb, const bf16* wvb,
    const float* bq, const float* bk, const float* bv,
    bf16* Qh, bf16* Kh, bf16* VhT)
{
  const bf16* A; const bf16* W; const float* bias; bf16* out; int mode;
  if (blockIdx.z == 0)      { A = qb; W = wqb; bias = bq; out = Qh;  mode = 3; }
  else if (blockIdx.z == 1) { A = kb; W = wkb; bias = bk; out = Kh;  mode = 0; }
  else                      { A = vb; W = wvb; bias = bv; out = VhT; mode = 2; }
  gemm_bt_body(A, W, bias, out, nullptr, blockIdx.y * 128, blockIdx.x * 128, mode);
}

__global__ __launch_bounds__(256, 2) void gemm_final_kernel(
    const bf16* Ob, const bf16* wob, const float* bo, float* out)
{
  gemm_bt_body(Ob, wob, bo, nullptr, out, blockIdx.y * 128, blockIdx.x * 128, 1);
}

// ---------------- flash attention v4: key-split waves ----------------
// Block = 2 waves on the SAME 32-row tile; wave w handles key chunks of
// parity w (additive softmax partials: no running max -> merge = sum).
// Grid (32 bh, 64 g) = 2048 blocks -> 8 blocks/CU = 4 waves/SIMD.
// CU's 8 blocks share one bh (id%32) and g ≡ r (mod 8); zigzag qt(g) makes
// per-CU chunk total exactly 132 (perfect balance). K dbuf-prefetched at
// stride 2; V loaded at chunk top, consumed after QK+softmax.
__global__ __launch_bounds__(128, 4) void attn_kernel(
    const bf16* __restrict__ Qh, const bf16* __restrict__ Kh,
    const bf16* __restrict__ VhT, bf16* __restrict__ Ob)
{
  __shared__ alignas(16) bf16 Ps[2][32 * 72];     // per-wave P round-trip slice
  __shared__ alignas(16) float Xo[2][4][64][4];   // [wave][j][lane][r]: o of slab 1-w
  __shared__ float Xl[2][64][4];                  // [wave][lane][r]: lsum of slab 1-w
  const int tid = threadIdx.x;
  const int wave = tid >> 6, lane = tid & 63;
  const int quad = lane >> 4, l15 = lane & 15;
  const int bh = blockIdx.x, g = blockIdx.y;
  const int b = bh >> 4, h = bh & 15;
  const int a = g >> 3, rr = g & 7;
  const int qt = 8 * a + ((a & 1) ? (7 - rr) : rr);
  const int L = qt >> 1;
  const bf16* Qb = Qh + (size_t)bh * Sq * 64;
  const bf16* Kb = Kh + (size_t)bh * Sq * 64;
  const bf16* Vb = VhT + (size_t)bh * 64 * Sq;
  bf16* Pw = &Ps[wave][0];
  const int r0 = qt * 32;

  // Q fragments (pre-scaled by 1/8 in projection): A[m=l15][k=quad*8+j]
  v8bf aq[2][2];
#pragma unroll
  for (int s = 0; s < 2; s++)
#pragma unroll
    for (int ks = 0; ks < 2; ks++)
      aq[s][ks] = *(const v8bf*)&Qb[(size_t)(r0 + s * 16 + l15) * 64 + ks * 32 + quad * 8];

  float lsum[2][4];
  v4f o[2][4];
#pragma unroll
  for (int s = 0; s < 2; s++)
#pragma unroll
    for (int r = 0; r < 4; r++) lsum[s][r] = 0.f;
#pragma unroll
  for (int s = 0; s < 2; s++)
#pragma unroll
    for (int j = 0; j < 4; j++) { v4f z = {0.f, 0.f, 0.f, 0.f}; o[s][j] = z; }

  auto loadK = [&](int kb, v8bf (&BK)[4][2]) {
#pragma unroll
    for (int n = 0; n < 4; n++) {
      BK[n][0] = *(const v8bf*)&Kb[(size_t)(kb + n * 16 + l15) * 64 + quad * 8];
      BK[n][1] = *(const v8bf*)&Kb[(size_t)(kb + n * 16 + l15) * 64 + 32 + quad * 8];
    }
  };
  auto loadV = [&](int kb, v8bf (&BV)[4][2]) {
#pragma unroll
    for (int n = 0; n < 4; n++) {
      BV[n][0] = *(const v8bf*)&Vb[(size_t)(n * 16 + l15) * 2048 + kb + quad * 8];
      BV[n][1] = *(const v8bf*)&Vb[(size_t)(n * 16 + l15) * 2048 + kb + 32 + quad * 8];
    }
  };
  auto compute = [&](const v8bf (&BK)[4][2], const v8bf (&BV)[4][2], int kc) {
    const int kbase = kc * 64;
    const bool diag = (kc == L);
#pragma unroll
    for (int s = 0; s < 2; s++) {
      v4f cn[4];
#pragma unroll
      for (int n = 0; n < 4; n++) {
        v4f z = {0.f, 0.f, 0.f, 0.f};
        cn[n] = MFMA16(aq[s][0], BK[n][0], z);
        cn[n] = MFMA16(aq[s][1], BK[n][1], cn[n]);
      }
      const int rbase = r0 + s * 16 + quad * 4;   // C-layout: row=quad*4+r, col=l15
#pragma unroll
      for (int n = 0; n < 4; n++) {
        const int colg = kbase + n * 16 + l15;
#pragma unroll
        for (int r = 0; r < 4; r++) {
          float e = __expf(cn[n][r]);
          if (diag && colg > rbase + r) e = 0.f;
          lsum[s][r] += e;
          Pw[(s * 16 + quad * 4 + r) * 72 + n * 16 + l15] = (bf16)e;
        }
      }
    }
    // PV: A-layout read of own wave's P (same-wave LDS ordering)
#pragma unroll
    for (int s = 0; s < 2; s++) {
      v8bf ap0 = *(const v8bf*)&Pw[(s * 16 + l15) * 72 + quad * 8];
      v8bf ap1 = *(const v8bf*)&Pw[(s * 16 + l15) * 72 + 32 + quad * 8];
#pragma unroll
      for (int j = 0; j < 4; j++) {
        o[s][j] = MFMA16(ap0, BV[j][0], o[s][j]);
        o[s][j] = MFMA16(ap1, BV[j][1], o[s][j]);
      }
    }
  };

  // chunks of parity `wave`: kc = wave, wave+2, ... <= L
  v8bf bk0[4][2], bk1[4][2], bvv[4][2];
  int kc = wave;
  if (kc <= L) {
    loadK(kc * 64, bk0);
    while (true) {
      loadV(kc * 64, bvv);
      if (kc + 2 <= L) loadK((kc + 2) * 64, bk1);
      compute(bk0, bvv, kc);
      kc += 2;
      if (kc > L) break;
      loadV(kc * 64, bvv);
      if (kc + 2 <= L) loadK((kc + 2) * 64, bk0);
      compute(bk1, bvv, kc);
      kc += 2;
      if (kc > L) break;
    }
  }

  // ---- merge: exchange slab (1-wave) partials, each wave stores slab `wave`
  const int ow = 1 - wave;
#pragma unroll
  for (int j = 0; j < 4; j++)
    *(v4f*)&Xo[wave][j][lane][0] = o[ow][j];
#pragma unroll
  for (int r = 0; r < 4; r++) Xl[wave][lane][r] = lsum[ow][r];
  __syncthreads();

  float ls[4];
#pragma unroll
  for (int r = 0; r < 4; r++) ls[r] = lsum[wave][r] + Xl[ow][lane][r];
#pragma unroll
  for (int off = 1; off < 16; off <<= 1)
#pragma unroll
    for (int r = 0; r < 4; r++) ls[r] += __shfl_xor(ls[r], off, 64);
  v4f om[4];
#pragma unroll
  for (int j = 0; j < 4; j++) om[j] = o[wave][j] + *(const v4f*)&Xo[ow][j][lane][0];
#pragma unroll
  for (int r = 0; r < 4; r++) {
    const float inv = 1.0f / ls[r];
    const int sg = r0 + wave * 16 + quad * 4 + r;
#pragma unroll
    for (int j = 0; j < 4; j++)
      Ob[((size_t)(b * Sq + sg)) * 1024 + h * 64 + j * 16 + l15] =
          (bf16)(om[j][r] * inv);
  }
}

// ---------------- launch ----------------
extern "C" void kernel_launch(void* const* d_in, const int* in_sizes, int n_in,
                              void* d_out, int out_size, void* d_ws, size_t ws_size,
                              hipStream_t stream) {
  (void)in_sizes; (void)n_in; (void)out_size; (void)ws_size;
  const float* kin = (const float*)d_in[0];
  const float* qin = (const float*)d_in[1];
  const float* vin = (const float*)d_in[2];
  const float* wq  = (const float*)d_in[3];
  const float* bq  = (const float*)d_in[4];
  const float* wk  = (const float*)d_in[5];
  const float* bk  = (const float*)d_in[6];
  const float* wv  = (const float*)d_in[7];
  const float* bv  = (const float*)d_in[8];
  const float* wo  = (const float*)d_in[9];
  const float* bo  = (const float*)d_in[10];

  bf16* ws = (bf16*)d_ws;
  bf16* qb  = ws;
  bf16* kb  = ws + NI;
  bf16* vb  = ws + 2 * NI;
  bf16* wqb = ws + 3 * NI;
  bf16* wkb = wqb + NW;
  bf16* wvb = wqb + 2 * NW;
  bf16* wob = wqb + 3 * NW;
  bf16* Qh  = ws + 3 * NI + 4 * NW;
  bf16* Kh  = Qh + NI;
  bf16* VhT = Qh + 2 * NI;
  bf16* Ob  = Qh + 3 * NI;

  convert_kernel<<<16384, 256, 0, stream>>>(qin, kin, vin, wq, wk, wv, wo, ws);
  gemm_proj_kernel<<<dim3(8, 32, 3), 256, 0, stream>>>(
      qb, kb, vb, wqb, wkb, wvb, bq, bk, bv, Qh, Kh, VhT);
  attn_kernel<<<dim3(32, 64), 128, 0, stream>>>(Qh, Kh, VhT, Ob);
  gemm_final_kernel<<<dim3(8, 32), 256, 0, stream>>>(Ob, wob, bo, (float*)d_out);
}

// Round 5
// 315.959 us; speedup vs baseline: 1.2835x; 1.2835x over previous
//
#include <hip/hip_runtime.h>

typedef __bf16 bf16;
typedef __bf16 v8bf __attribute__((ext_vector_type(8)));
typedef __bf16 v4bf __attribute__((ext_vector_type(4)));
typedef float  v4f  __attribute__((ext_vector_type(4)));

#define MFMA16(a,b,c) __builtin_amdgcn_mfma_f32_16x16x32_bf16((a),(b),(c),0,0,0)

// B=2, S=2048, D=1024, H=16, DK=64
static constexpr int Sq = 2048;
static constexpr size_t NI = 4194304;  // B*S*D
static constexpr size_t NW = 1048576;  // D*D

__device__ __forceinline__ void gld_lds16(const void* g, void* l) {
  __builtin_amdgcn_global_load_lds(
      (__attribute__((address_space(1))) unsigned int*)g,
      (__attribute__((address_space(3))) unsigned int*)l,
      16, 0, 0);
}

// ---------------- convert fp32 -> bf16 (q,k,v,wq,wk,wv,wo) ----------------
__global__ __launch_bounds__(256) void convert_kernel(
    const float* __restrict__ q, const float* __restrict__ k, const float* __restrict__ v,
    const float* __restrict__ wq, const float* __restrict__ wk,
    const float* __restrict__ wv, const float* __restrict__ wo,
    bf16* __restrict__ dst)
{
  const int NI4 = 1048576;  // NI/4 = 2^20
  const int NW4 = 262144;   // NW/4 = 2^18
  int idx = blockIdx.x * 256 + threadIdx.x;   // total 4194304
  const float* src; size_t dstoff; int local;
  if (idx < 3 * NI4) {
    int a = idx >> 20; local = idx & (NI4 - 1);
    src = (a == 0) ? q : ((a == 1) ? k : v);
    dstoff = (size_t)a * NI;
  } else {
    int t = idx - 3 * NI4;
    int a = t >> 18; local = t & (NW4 - 1);
    src = (a == 0) ? wq : ((a == 1) ? wk : ((a == 2) ? wv : wo));
    dstoff = 3 * NI + (size_t)a * NW;
  }
  float4 f = ((const float4*)src)[local];
  v4bf hv = { (bf16)f.x, (bf16)f.y, (bf16)f.z, (bf16)f.w };
  *(v4bf*)(dst + dstoff + (size_t)local * 4) = hv;
}

// ---------------- m97-style GEMM: C = A(MxK) * Bw(NxK)^T + bias ----------------
// mode 0: bf16 headsplit [B,H,S,DK]; mode 3: same with *0.125 (Q pre-scale);
// mode 2: bf16 VhT [B,H,DK,S] (8B stores); mode 1: f32 row-major.
__device__ __forceinline__ void gemm_bt_body(
    const bf16* __restrict__ A, const bf16* __restrict__ Bw,
    const float* __restrict__ bias, bf16* __restrict__ outh,
    float* __restrict__ outf, int bm, int bn, int mode)
{
  __shared__ alignas(16) bf16 As[128 * 32];
  __shared__ alignas(16) bf16 Bs[128 * 32];
  const int tid = threadIdx.x;
  const int wave = tid >> 6, lane = tid & 63;
  const int quad = lane >> 4, l15 = lane & 15;
  const int wm = (wave >> 1) * 64, wn = (wave & 1) * 64;
  const int lrow = lane >> 2, lcol = (lane & 3) * 8;

  v4f acc[4][4];
#pragma unroll
  for (int i = 0; i < 4; i++)
#pragma unroll
    for (int j = 0; j < 4; j++) { v4f z = {0.f, 0.f, 0.f, 0.f}; acc[i][j] = z; }

  const bf16* gA = A  + (size_t)(bm + wave * 32 + lrow) * 1024 + lcol;
  const bf16* gB = Bw + (size_t)(bn + wave * 32 + lrow) * 1024 + lcol;
  bf16* lA0 = &As[(wave * 32) * 32];
  bf16* lA1 = &As[(wave * 32 + 16) * 32];
  bf16* lB0 = &Bs[(wave * 32) * 32];
  bf16* lB1 = &Bs[(wave * 32 + 16) * 32];

  for (int k0 = 0; k0 < 1024; k0 += 32) {
    gld_lds16(gA + k0, lA0);
    gld_lds16(gA + 16 * 1024 + k0, lA1);
    gld_lds16(gB + k0, lB0);
    gld_lds16(gB + 16 * 1024 + k0, lB1);
    __syncthreads();
    v8bf af[4], bfr[4];
#pragma unroll
    for (int i = 0; i < 4; i++)
      af[i] = *(const v8bf*)&As[(wm + i * 16 + l15) * 32 + quad * 8];
#pragma unroll
    for (int j = 0; j < 4; j++)
      bfr[j] = *(const v8bf*)&Bs[(wn + j * 16 + l15) * 32 + quad * 8];
#pragma unroll
    for (int i = 0; i < 4; i++)
#pragma unroll
      for (int j = 0; j < 4; j++)
        acc[i][j] = MFMA16(af[i], bfr[j], acc[i][j]);
    __syncthreads();
  }

#pragma unroll
  for (int i = 0; i < 4; i++) {
    const int m0 = bm + wm + i * 16 + quad * 4;
#pragma unroll
    for (int j = 0; j < 4; j++) {
      const int n = bn + wn + j * 16 + l15;
      const float bv = bias[n];
      if (mode == 1) {
#pragma unroll
        for (int r = 0; r < 4; r++)
          outf[(size_t)(m0 + r) * 1024 + n] = acc[i][j][r] + bv;
      } else if (mode == 2) {
        // VhT[bh][dk][s]: consecutive r -> consecutive s -> 8B vector store
        int b_ = m0 >> 11, s_ = m0 & 2047;
        int h_ = n >> 6,  dk = n & 63;
        v4bf pk;
#pragma unroll
        for (int r = 0; r < 4; r++) pk[r] = (bf16)(acc[i][j][r] + bv);
        *(v4bf*)&outh[((size_t)((b_ * 16 + h_) * 64 + dk)) * 2048 + s_] = pk;
      } else {
        const float sc = (mode == 3) ? 0.125f : 1.0f;
        int h_ = n >> 6,  dk = n & 63;
#pragma unroll
        for (int r = 0; r < 4; r++) {
          int m = m0 + r;
          int b_ = m >> 11, s_ = m & 2047;
          outh[(((size_t)(b_ * 16 + h_) * 2048 + s_) << 6) + dk] =
              (bf16)((acc[i][j][r] + bv) * sc);
        }
      }
    }
  }
}

__global__ __launch_bounds__(256, 2) void gemm_proj_kernel(
    const bf16* qb, const bf16* kb, const bf16* vb,
    const bf16* wqb, const bf16* wkb, const bf16* wvb,
    const float* bq, const float* bk, const float* bv,
    bf16* Qh, bf16* Kh, bf16* VhT)
{
  const bf16* A; const bf16* W; const float* bias; bf16* out; int mode;
  if (blockIdx.z == 0)      { A = qb; W = wqb; bias = bq; out = Qh;  mode = 3; }
  else if (blockIdx.z == 1) { A = kb; W = wkb; bias = bk; out = Kh;  mode = 0; }
  else                      { A = vb; W = wvb; bias = bv; out = VhT; mode = 2; }
  gemm_bt_body(A, W, bias, out, nullptr, blockIdx.y * 128, blockIdx.x * 128, mode);
}

__global__ __launch_bounds__(256, 2) void gemm_final_kernel(
    const bf16* Ob, const bf16* wob, const float* bo, float* out)
{
  gemm_bt_body(Ob, wob, bo, nullptr, out, blockIdx.y * 128, blockIdx.x * 128, 1);
}

// ---------------- flash attention v5: slab+parity split, 4 waves/tile ----------------
// Block = 256 thr = 4 waves on ONE 32-row Q tile. wave w: slab s=w>>1 (16 rows),
// parity p=w&1 (key chunks kc ≡ p mod 2). Additive softmax partials (no running
// max -> merge is a plain sum through LDS). Per-wave regs ~110 -> fits 128 cap
// at 4 waves/SIMD (no spill; R4's launch_bounds(128,4) forced VGPR=64 + 423 MB
// scratch spill). Grid (32 bh, 64 g) = 2048 blocks -> ~5 blocks/CU.
__global__ __launch_bounds__(256, 4) void attn_kernel(
    const bf16* __restrict__ Qh, const bf16* __restrict__ Kh,
    const bf16* __restrict__ VhT, bf16* __restrict__ Ob)
{
  __shared__ alignas(16) bf16 Ps[4][16 * 72];     // per-wave P round-trip slice
  __shared__ alignas(16) float Xo[4][4][64][4];   // [wave][j][lane][r] o-partials
  __shared__ float Xl[4][64][4];                  // [wave][lane][r] lsum-partials
  const int tid = threadIdx.x;
  const int wave = tid >> 6, lane = tid & 63;
  const int slab = wave >> 1, par = wave & 1;
  const int quad = lane >> 4, l15 = lane & 15;
  const int bh = blockIdx.x, g = blockIdx.y;
  const int b = bh >> 4, h = bh & 15;
  const int a = g >> 3, rr = g & 7;
  const int qt = 8 * a + ((a & 1) ? (7 - rr) : rr);   // zigzag: per-CU balance
  const int L = qt >> 1;
  const bf16* Qb = Qh + (size_t)bh * Sq * 64;
  const bf16* Kb = Kh + (size_t)bh * Sq * 64;
  const bf16* Vb = VhT + (size_t)bh * 64 * Sq;
  bf16* Pw = &Ps[wave][0];
  const int r0 = qt * 32;
  const int rs0 = r0 + slab * 16;                 // this wave's 16 rows

  // Q fragments for this slab (pre-scaled by 1/8): A[m=l15][k=quad*8+j]
  v8bf aq[2];
#pragma unroll
  for (int ks = 0; ks < 2; ks++)
    aq[ks] = *(const v8bf*)&Qb[(size_t)(rs0 + l15) * 64 + ks * 32 + quad * 8];

  float lsum[4] = {0.f, 0.f, 0.f, 0.f};
  v4f o[4];
#pragma unroll
  for (int j = 0; j < 4; j++) { v4f z = {0.f, 0.f, 0.f, 0.f}; o[j] = z; }

  for (int kc = par; kc <= L; kc += 2) {
    const int kbase = kc * 64;
    v8bf bk[4][2], bv[4][2];
#pragma unroll
    for (int n = 0; n < 4; n++) {
      bk[n][0] = *(const v8bf*)&Kb[(size_t)(kbase + n * 16 + l15) * 64 + quad * 8];
      bk[n][1] = *(const v8bf*)&Kb[(size_t)(kbase + n * 16 + l15) * 64 + 32 + quad * 8];
      bv[n][0] = *(const v8bf*)&Vb[(size_t)(n * 16 + l15) * 2048 + kbase + quad * 8];
      bv[n][1] = *(const v8bf*)&Vb[(size_t)(n * 16 + l15) * 2048 + kbase + 32 + quad * 8];
    }
    // QK^T for 16 rows x 64 keys
    v4f cn[4];
#pragma unroll
    for (int n = 0; n < 4; n++) {
      v4f z = {0.f, 0.f, 0.f, 0.f};
      cn[n] = MFMA16(aq[0], bk[n][0], z);
      cn[n] = MFMA16(aq[1], bk[n][1], cn[n]);
    }
    const int rbase = rs0 + quad * 4;            // C-layout: row=quad*4+r, col=l15
    const bool diag = (kc == L);
#pragma unroll
    for (int n = 0; n < 4; n++) {
      const int colg = kbase + n * 16 + l15;
#pragma unroll
      for (int r = 0; r < 4; r++) {
        float e = __expf(cn[n][r]);
        if (diag && colg > rbase + r) e = 0.f;
        lsum[r] += e;
        Pw[(quad * 4 + r) * 72 + n * 16 + l15] = (bf16)e;
      }
    }
    // PV: A-layout read of own wave's P (same-wave LDS ordering, no barrier)
    v8bf ap0 = *(const v8bf*)&Pw[l15 * 72 + quad * 8];
    v8bf ap1 = *(const v8bf*)&Pw[l15 * 72 + 32 + quad * 8];
#pragma unroll
    for (int j = 0; j < 4; j++) {
      o[j] = MFMA16(ap0, bv[j][0], o[j]);
      o[j] = MFMA16(ap1, bv[j][1], o[j]);
    }
  }

  // ---- merge parity partials (pure sums), p==0 wave of each slab finalizes
#pragma unroll
  for (int j = 0; j < 4; j++)
    *(v4f*)&Xo[wave][j][lane][0] = o[j];
#pragma unroll
  for (int r = 0; r < 4; r++) Xl[wave][lane][r] = lsum[r];
  __syncthreads();
  if (par == 0) {
    const int pw = wave + 1;   // partner parity-1 wave, same slab
    float ls[4];
#pragma unroll
    for (int r = 0; r < 4; r++) ls[r] = lsum[r] + Xl[pw][lane][r];
#pragma unroll
    for (int off = 1; off < 16; off <<= 1)
#pragma unroll
      for (int r = 0; r < 4; r++) ls[r] += __shfl_xor(ls[r], off, 64);
#pragma unroll
    for (int r = 0; r < 4; r++) {
      const float inv = 1.0f / ls[r];
      const int sg = rs0 + quad * 4 + r;
#pragma unroll
      for (int j = 0; j < 4; j++) {
        float om = o[j][r] + Xo[pw][j][lane][r];
        Ob[((size_t)(b * Sq + sg)) * 1024 + h * 64 + j * 16 + l15] =
            (bf16)(om * inv);
      }
    }
  }
}

// ---------------- launch ----------------
extern "C" void kernel_launch(void* const* d_in, const int* in_sizes, int n_in,
                              void* d_out, int out_size, void* d_ws, size_t ws_size,
                              hipStream_t stream) {
  (void)in_sizes; (void)n_in; (void)out_size; (void)ws_size;
  const float* kin = (const float*)d_in[0];
  const float* qin = (const float*)d_in[1];
  const float* vin = (const float*)d_in[2];
  const float* wq  = (const float*)d_in[3];
  const float* bq  = (const float*)d_in[4];
  const float* wk  = (const float*)d_in[5];
  const float* bk  = (const float*)d_in[6];
  const float* wv  = (const float*)d_in[7];
  const float* bv  = (const float*)d_in[8];
  const float* wo  = (const float*)d_in[9];
  const float* bo  = (const float*)d_in[10];

  bf16* ws = (bf16*)d_ws;
  bf16* qb  = ws;
  bf16* kb  = ws + NI;
  bf16* vb  = ws + 2 * NI;
  bf16* wqb = ws + 3 * NI;
  bf16* wkb = wqb + NW;
  bf16* wvb = wqb + 2 * NW;
  bf16* wob = wqb + 3 * NW;
  bf16* Qh  = ws + 3 * NI + 4 * NW;
  bf16* Kh  = Qh + NI;
  bf16* VhT = Qh + 2 * NI;
  bf16* Ob  = Qh + 3 * NI;

  convert_kernel<<<16384, 256, 0, stream>>>(qin, kin, vin, wq, wk, wv, wo, ws);
  gemm_proj_kernel<<<dim3(8, 32, 3), 256, 0, stream>>>(
      qb, kb, vb, wqb, wkb, wvb, bq, bk, bv, Qh, Kh, VhT);
  attn_kernel<<<dim3(32, 64), 256, 0, stream>>>(Qh, Kh, VhT, Ob);
  gemm_final_kernel<<<dim3(8, 32), 256, 0, stream>>>(Ob, wob, bo, (float*)d_out);
}

// Round 7
// 269.855 us; speedup vs baseline: 1.5028x; 1.1708x over previous
//
#include <hip/hip_runtime.h>

typedef __bf16 bf16;
typedef __bf16 v8bf __attribute__((ext_vector_type(8)));
typedef __bf16 v4bf __attribute__((ext_vector_type(4)));
typedef float  v4f  __attribute__((ext_vector_type(4)));

#define MFMA16(a,b,c) __builtin_amdgcn_mfma_f32_16x16x32_bf16((a),(b),(c),0,0,0)

// B=2, S=2048, D=1024, H=16, DK=64
static constexpr int Sq = 2048;
static constexpr size_t NI = 4194304;  // B*S*D
static constexpr size_t NW = 1048576;  // D*D

__device__ __forceinline__ void gld_lds16(const void* g, void* l) {
  __builtin_amdgcn_global_load_lds(
      (__attribute__((address_space(1))) unsigned int*)g,
      (__attribute__((address_space(3))) unsigned int*)l,
      16, 0, 0);
}

// ---------------- convert fp32 -> bf16 (q,k,v,wq,wk,wv,wo) ----------------
__global__ __launch_bounds__(256) void convert_kernel(
    const float* __restrict__ q, const float* __restrict__ k, const float* __restrict__ v,
    const float* __restrict__ wq, const float* __restrict__ wk,
    const float* __restrict__ wv, const float* __restrict__ wo,
    bf16* __restrict__ dst)
{
  const int NI4 = 1048576;  // NI/4 = 2^20
  const int NW4 = 262144;   // NW/4 = 2^18
  int idx = blockIdx.x * 256 + threadIdx.x;   // total 4194304
  const float* src; size_t dstoff; int local;
  if (idx < 3 * NI4) {
    int a = idx >> 20; local = idx & (NI4 - 1);
    src = (a == 0) ? q : ((a == 1) ? k : v);
    dstoff = (size_t)a * NI;
  } else {
    int t = idx - 3 * NI4;
    int a = t >> 18; local = t & (NW4 - 1);
    src = (a == 0) ? wq : ((a == 1) ? wk : ((a == 2) ? wv : wo));
    dstoff = 3 * NI + (size_t)a * NW;
  }
  float4 f = ((const float4*)src)[local];
  v4bf hv = { (bf16)f.x, (bf16)f.y, (bf16)f.z, (bf16)f.w };
  *(v4bf*)(dst + dstoff + (size_t)local * 4) = hv;
}

// ---------------- m97-style GEMM: C = A(MxK) * Bw(NxK)^T + bias ----------------
// mode 0: bf16 headsplit [B,H,S,DK]; mode 3: same with *0.125*log2(e) (Q pre-scale);
// mode 2: bf16 VhT [B,H,DK,S] (8B stores); mode 1: f32 row-major.
__device__ __forceinline__ void gemm_bt_body(
    const bf16* __restrict__ A, const bf16* __restrict__ Bw,
    const float* __restrict__ bias, bf16* __restrict__ outh,
    float* __restrict__ outf, int bm, int bn, int mode)
{
  __shared__ alignas(16) bf16 As[128 * 32];
  __shared__ alignas(16) bf16 Bs[128 * 32];
  const int tid = threadIdx.x;
  const int wave = tid >> 6, lane = tid & 63;
  const int quad = lane >> 4, l15 = lane & 15;
  const int wm = (wave >> 1) * 64, wn = (wave & 1) * 64;
  const int lrow = lane >> 2, lcol = (lane & 3) * 8;

  v4f acc[4][4];
#pragma unroll
  for (int i = 0; i < 4; i++)
#pragma unroll
    for (int j = 0; j < 4; j++) { v4f z = {0.f, 0.f, 0.f, 0.f}; acc[i][j] = z; }

  const bf16* gA = A  + (size_t)(bm + wave * 32 + lrow) * 1024 + lcol;
  const bf16* gB = Bw + (size_t)(bn + wave * 32 + lrow) * 1024 + lcol;
  bf16* lA0 = &As[(wave * 32) * 32];
  bf16* lA1 = &As[(wave * 32 + 16) * 32];
  bf16* lB0 = &Bs[(wave * 32) * 32];
  bf16* lB1 = &Bs[(wave * 32 + 16) * 32];

  for (int k0 = 0; k0 < 1024; k0 += 32) {
    gld_lds16(gA + k0, lA0);
    gld_lds16(gA + 16 * 1024 + k0, lA1);
    gld_lds16(gB + k0, lB0);
    gld_lds16(gB + 16 * 1024 + k0, lB1);
    __syncthreads();
    v8bf af[4], bfr[4];
#pragma unroll
    for (int i = 0; i < 4; i++)
      af[i] = *(const v8bf*)&As[(wm + i * 16 + l15) * 32 + quad * 8];
#pragma unroll
    for (int j = 0; j < 4; j++)
      bfr[j] = *(const v8bf*)&Bs[(wn + j * 16 + l15) * 32 + quad * 8];
#pragma unroll
    for (int i = 0; i < 4; i++)
#pragma unroll
      for (int j = 0; j < 4; j++)
        acc[i][j] = MFMA16(af[i], bfr[j], acc[i][j]);
    __syncthreads();
  }

#pragma unroll
  for (int i = 0; i < 4; i++) {
    const int m0 = bm + wm + i * 16 + quad * 4;
#pragma unroll
    for (int j = 0; j < 4; j++) {
      const int n = bn + wn + j * 16 + l15;
      const float bv = bias[n];
      if (mode == 1) {
#pragma unroll
        for (int r = 0; r < 4; r++)
          outf[(size_t)(m0 + r) * 1024 + n] = acc[i][j][r] + bv;
      } else if (mode == 2) {
        // VhT[bh][dk][s]: consecutive r -> consecutive s -> 8B vector store
        int b_ = m0 >> 11, s_ = m0 & 2047;
        int h_ = n >> 6,  dk = n & 63;
        v4bf pk;
#pragma unroll
        for (int r = 0; r < 4; r++) pk[r] = (bf16)(acc[i][j][r] + bv);
        *(v4bf*)&outh[((size_t)((b_ * 16 + h_) * 64 + dk)) * 2048 + s_] = pk;
      } else {
        // 0.125 * log2(e): attn uses exp2 -> saves a v_mul per score element
        const float sc = (mode == 3) ? 0.18033688011112042f : 1.0f;
        int h_ = n >> 6,  dk = n & 63;
#pragma unroll
        for (int r = 0; r < 4; r++) {
          int m = m0 + r;
          int b_ = m >> 11, s_ = m & 2047;
          outh[(((size_t)(b_ * 16 + h_) * 2048 + s_) << 6) + dk] =
              (bf16)((acc[i][j][r] + bv) * sc);
        }
      }
    }
  }
}

__global__ __launch_bounds__(256, 2) void gemm_proj_kernel(
    const bf16* qb, const bf16* kb, const bf16* vb,
    const bf16* wqb, const bf16* wkb, const bf16* wvb,
    const float* bq, const float* bk, const float* bv,
    bf16* Qh, bf16* Kh, bf16* VhT)
{
  const bf16* A; const bf16* W; const float* bias; bf16* out; int mode;
  if (blockIdx.z == 0)      { A = qb; W = wqb; bias = bq; out = Qh;  mode = 3; }
  else if (blockIdx.z == 1) { A = kb; W = wkb; bias = bk; out = Kh;  mode = 0; }
  else                      { A = vb; W = wvb; bias = bv; out = VhT; mode = 2; }
  gemm_bt_body(A, W, bias, out, nullptr, blockIdx.y * 128, blockIdx.x * 128, mode);
}

__global__ __launch_bounds__(256, 2) void gemm_final_kernel(
    const bf16* Ob, const bf16* wob, const float* bo, float* out)
{
  gemm_bt_body(Ob, wob, bo, nullptr, out, blockIdx.y * 128, blockIdx.x * 128, 1);
}

// ---------------- flash attention v6b: S^T orientation (fixed P slice) ----------------
// R3 grid/pairing (1024 blocks, 2 lockstep waves on tiles 2u,2u+1) with S^T =
// K·Q^T: C row=key, col=qrow=l15. Lane's 4 C values share qrow, span 4
// consecutive keys -> P round-trip = 8 ds_write_b64 + 8 ds_read_b128 per chunk
// in a [qrow][key] 16x72 per-wave slice (reused across both nt slabs; R6 bug
// was rb=nt*16+l15 overflowing into the other wave's slice). 16B-chunk XOR
// swizzle by l15&7. PV computes O^T = VhT·P^T; epilogue 8B stores; lsum scalar
// per lane (2 shfls, epilogue only). Q pre-scaled by 0.125*log2e -> exp2f.
__global__ __launch_bounds__(128, 2) void attn_kernel(
    const bf16* __restrict__ Qh, const bf16* __restrict__ Kh,
    const bf16* __restrict__ VhT, bf16* __restrict__ Ob)
{
  __shared__ alignas(16) bf16 Ps[2][16 * 72];   // per wave: 16 qrows x 72 (64+pad)
  const int tid = threadIdx.x;
  const int wave = tid >> 6, lane = tid & 63;
  const int quad = lane >> 4, l15 = lane & 15;
  const int bh = blockIdx.x, gy = blockIdx.y;
  const int b = bh >> 4, h = bh & 15;
  const int r8 = gy & 7, q8 = gy >> 3;
  const int u = 8 * q8 + ((q8 & 1) ? (7 - r8) : r8);
  const int qt = 2 * u + wave;                  // both waves: chunks 0..u
  const int L = u;
  const bf16* Qb = Qh + (size_t)bh * Sq * 64;
  const bf16* Kb = Kh + (size_t)bh * Sq * 64;
  const bf16* Vb = VhT + (size_t)bh * 64 * Sq;
  bf16* Pw = &Ps[wave][0];
  const int r0 = qt * 32;
  const int xk = l15 & 7;                       // XOR swizzle key (row = l15)

  // Q fragments as B-operand (n=qrow=l15, k=quad*8+j)
  v8bf bq[2][2];
#pragma unroll
  for (int nt = 0; nt < 2; nt++)
#pragma unroll
    for (int ks = 0; ks < 2; ks++)
      bq[nt][ks] = *(const v8bf*)&Qb[(size_t)(r0 + nt * 16 + l15) * 64 + ks * 32 + quad * 8];

  float lsum[2] = {0.f, 0.f};                   // per-lane partial, qrow = l15
  v4f o[2][4];                                  // O^T acc: [qrow-tile][dk-tile]
#pragma unroll
  for (int nt = 0; nt < 2; nt++)
#pragma unroll
    for (int j = 0; j < 4; j++) { v4f z = {0.f, 0.f, 0.f, 0.f}; o[nt][j] = z; }

  auto loadK = [&](int kb, v8bf (&AK)[4][2]) {  // K as A-operand (m=key)
#pragma unroll
    for (int m = 0; m < 4; m++) {
      AK[m][0] = *(const v8bf*)&Kb[(size_t)(kb + m * 16 + l15) * 64 + quad * 8];
      AK[m][1] = *(const v8bf*)&Kb[(size_t)(kb + m * 16 + l15) * 64 + 32 + quad * 8];
    }
  };
  auto loadV = [&](int kb, v8bf (&AV)[4][2]) {  // VhT as A-operand (m=dk)
#pragma unroll
    for (int j = 0; j < 4; j++) {
      AV[j][0] = *(const v8bf*)&Vb[(size_t)(j * 16 + l15) * 2048 + kb + quad * 8];
      AV[j][1] = *(const v8bf*)&Vb[(size_t)(j * 16 + l15) * 2048 + kb + 32 + quad * 8];
    }
  };
  auto compute = [&](const v8bf (&AK)[4][2], const v8bf (&AV)[4][2], int kc) {
    const int kbase = kc * 64;
    const bool diag = (kc == L);
#pragma unroll
    for (int nt = 0; nt < 2; nt++) {
      // S^T tile: rows = keys (4 m-tiles), cols = qrow (l15)
      v4f cn[4];
#pragma unroll
      for (int m = 0; m < 4; m++) {
        v4f z = {0.f, 0.f, 0.f, 0.f};
        cn[m] = MFMA16(AK[m][0], bq[nt][0], z);
        cn[m] = MFMA16(AK[m][1], bq[nt][1], cn[m]);
      }
      const int qrow = r0 + nt * 16 + l15;
      const int rb = l15;                       // 16-row slice reused per nt
#pragma unroll
      for (int m = 0; m < 4; m++) {
        const int keyb = kbase + m * 16 + quad * 4;   // C row = quad*4+r
        v4bf pk;
#pragma unroll
        for (int r = 0; r < 4; r++) {
          float e = exp2f(cn[m][r]);
          if (diag && (keyb + r > qrow)) e = 0.f;
          lsum[nt] += e;
          pk[r] = (bf16)e;
        }
        // swizzled b64 store: chunk = 2m + (quad>>1), sub = (quad&1)*4
        const int ch = (2 * m + (quad >> 1)) ^ xk;
        *(v4bf*)&Pw[rb * 72 + ch * 8 + (quad & 1) * 4] = pk;
      }
      // P^T as B-operand (n=qrow=l15, k=key contiguous): swizzled b128 reads
#pragma unroll
      for (int ks = 0; ks < 2; ks++) {
        const int ch = (4 * ks + quad) ^ xk;
        v8bf bp = *(const v8bf*)&Pw[rb * 72 + ch * 8];
#pragma unroll
        for (int j = 0; j < 4; j++)
          o[nt][j] = MFMA16(AV[j][ks], bp, o[nt][j]);
      }
    }
  };

  v8bf ak0[4][2], ak1[4][2], avv[4][2];
  loadK(0, ak0);
  int kc = 0;
  while (true) {
    loadV(kc * 64, avv);
    if (kc < L) loadK((kc + 1) * 64, ak1);
    compute(ak0, avv, kc);
    if (++kc > L) break;
    loadV(kc * 64, avv);
    if (kc < L) loadK((kc + 1) * 64, ak0);
    compute(ak1, avv, kc);
    if (++kc > L) break;
  }

  // epilogue: reduce lsum across the 4 quads (keys), normalize, store O^T
#pragma unroll
  for (int nt = 0; nt < 2; nt++) {
    lsum[nt] += __shfl_xor(lsum[nt], 16, 64);
    lsum[nt] += __shfl_xor(lsum[nt], 32, 64);
  }
#pragma unroll
  for (int nt = 0; nt < 2; nt++) {
    const float inv = 1.0f / lsum[nt];
    const int qrow = r0 + nt * 16 + l15;
    bf16* dst = Ob + ((size_t)(b * Sq + qrow)) * 1024 + h * 64 + quad * 4;
#pragma unroll
    for (int j = 0; j < 4; j++) {
      v4bf pk;
#pragma unroll
      for (int r = 0; r < 4; r++) pk[r] = (bf16)(o[nt][j][r] * inv);
      *(v4bf*)(dst + j * 16) = pk;
    }
  }
}

// ---------------- launch ----------------
extern "C" void kernel_launch(void* const* d_in, const int* in_sizes, int n_in,
                              void* d_out, int out_size, void* d_ws, size_t ws_size,
                              hipStream_t stream) {
  (void)in_sizes; (void)n_in; (void)out_size; (void)ws_size;
  const float* kin = (const float*)d_in[0];
  const float* qin = (const float*)d_in[1];
  const float* vin = (const float*)d_in[2];
  const float* wq  = (const float*)d_in[3];
  const float* bq  = (const float*)d_in[4];
  const float* wk  = (const float*)d_in[5];
  const float* bk  = (const float*)d_in[6];
  const float* wv  = (const float*)d_in[7];
  const float* bv  = (const float*)d_in[8];
  const float* wo  = (const float*)d_in[9];
  const float* bo  = (const float*)d_in[10];

  bf16* ws = (bf16*)d_ws;
  bf16* qb  = ws;
  bf16* kb  = ws + NI;
  bf16* vb  = ws + 2 * NI;
  bf16* wqb = ws + 3 * NI;
  bf16* wkb = wqb + NW;
  bf16* wvb = wqb + 2 * NW;
  bf16* wob = wqb + 3 * NW;
  bf16* Qh  = ws + 3 * NI + 4 * NW;
  bf16* Kh  = Qh + NI;
  bf16* VhT = Qh + 2 * NI;
  bf16* Ob  = Qh + 3 * NI;

  convert_kernel<<<16384, 256, 0, stream>>>(qin, kin, vin, wq, wk, wv, wo, ws);
  gemm_proj_kernel<<<dim3(8, 32, 3), 256, 0, stream>>>(
      qb, kb, vb, wqb, wkb, wvb, bq, bk, bv, Qh, Kh, VhT);
  attn_kernel<<<dim3(32, 32), 128, 0, stream>>>(Qh, Kh, VhT, Ob);
  gemm_final_kernel<<<dim3(8, 32), 256, 0, stream>>>(Ob, wob, bo, (float*)d_out);
}